// Round 3
// baseline (589.687 us; speedup 1.0000x reference)
//
#include <hip/hip_runtime.h>

typedef unsigned short ushort_t;
typedef __attribute__((ext_vector_type(8))) __bf16 bf16x8;
typedef __attribute__((ext_vector_type(8))) unsigned short ushort8;
typedef __attribute__((ext_vector_type(4))) float f32x4;
typedef __attribute__((ext_vector_type(4))) unsigned int uint4v;

#define N_NODES 8192
#define NODE_MASK 8191
#define E_EDGES 32768
#define E_TOT   40960   /* E + N self loops */
#define M_MASK  2048
#define D_IN    768
#define C_CH    768
#define F1      6144    /* 8 heads * 768 */

__device__ __forceinline__ float bf2f(ushort_t u) {
    union { unsigned int i; float f; } v; v.i = ((unsigned int)u) << 16; return v.f;
}
__device__ __forceinline__ ushort_t f2bf(float f) {
    union { float f; unsigned int i; } v; v.f = f;
    unsigned int r = v.i + 0x7fffu + ((v.i >> 16) & 1u);
    return (ushort_t)(r >> 16);
}

// ---------------------------------------------------------------------------
// int64-vs-int32 detection + conversion of index arrays (clamped to [0,N)).
// int64 values < 2^32 have all odd 32-bit words zero.
// ---------------------------------------------------------------------------
__global__ void init_kernel(int* deg, int* fill, int* flags) {
    int i = blockIdx.x * 256 + threadIdx.x;
    if (i < N_NODES) { deg[i] = 0; fill[i] = 0; }
    if (i < 2) flags[i] = 0;
}
__global__ void detect_kernel(const int* __restrict__ raw, int nhalf, int* __restrict__ flag) {
    int i = blockIdx.x * 256 + threadIdx.x;
    if (i < nhalf && raw[2 * i + 1] != 0) atomicOr(flag, 1);  // evidence of int32 data
}
__global__ void convert_idx_kernel(const void* __restrict__ raw, int n,
                                   const int* __restrict__ flag, int* __restrict__ out) {
    int i = blockIdx.x * 256 + threadIdx.x;
    if (i >= n) return;
    int v = (*flag) ? ((const int*)raw)[i] : (int)((const long long*)raw)[i];
    out[i] = v & NODE_MASK;
}

// ---------------------------------------------------------------------------
// f32 -> bf16 elementwise convert (vectorized)
// ---------------------------------------------------------------------------
__global__ void cvt_bf16_kernel(const float* __restrict__ in, ushort_t* __restrict__ out, int n4) {
    int i = blockIdx.x * 256 + threadIdx.x;
    if (i >= n4) return;
    f32x4 v = *(const f32x4*)(in + i * 4);
    ushort_t o0 = f2bf(v[0]), o1 = f2bf(v[1]), o2 = f2bf(v[2]), o3 = f2bf(v[3]);
    unsigned long long pk = (unsigned long long)o0 | ((unsigned long long)o1 << 16)
                          | ((unsigned long long)o2 << 32) | ((unsigned long long)o3 << 48);
    *(unsigned long long*)(out + i * 4) = pk;
}

// ---------------------------------------------------------------------------
// f32 -> bf16 transpose: out[c][r] = (bf16)in[r][c]; in is R x Ccols f32.
// ---------------------------------------------------------------------------
__global__ __launch_bounds__(256) void transpose_cvt_kernel(
    const float* __restrict__ in, ushort_t* __restrict__ out, int R, int Ccols)
{
    __shared__ ushort_t tile[32][33];
    int tx = threadIdx.x & 31, ty = threadIdx.x >> 5;
    int x  = blockIdx.x * 32 + tx;
    int y0 = blockIdx.y * 32;
#pragma unroll
    for (int i = 0; i < 4; ++i)
        tile[ty + i * 8][tx] = f2bf(in[(size_t)(y0 + ty + i * 8) * Ccols + x]);
    __syncthreads();
#pragma unroll
    for (int i = 0; i < 4; ++i)
        out[(size_t)(blockIdx.x * 32 + ty + i * 8) * R + y0 + tx] = tile[tx][ty + i * 8];
}

// ---------------------------------------------------------------------------
// bf16 MFMA GEMM:  C[M,N] = A[M,K] * Bt[N,K]^T  (+ optional f32 bias[N]) -> bf16
// 128x128 tile, BK=64, 256 threads (4 waves, each 64x64 via 4x4 MFMA 16x16x32)
// XOR-swizzled LDS (16B chunks) -> aligned b128 LDS ops, <=2-way bank alias.
// ---------------------------------------------------------------------------
__global__ __launch_bounds__(256) void gemm_bt_kernel(
    const ushort_t* __restrict__ A, const ushort_t* __restrict__ Bt,
    ushort_t* __restrict__ C, const float* __restrict__ bias,
    int M, int N, int K)
{
    __shared__ ushort_t lsA[128 * 64];
    __shared__ ushort_t lsB[128 * 64];

    const int tid  = threadIdx.x;
    const int lane = tid & 63;
    const int wave = tid >> 6;
    const int wm = wave >> 1, wn = wave & 1;
    const int bx = blockIdx.x, by = blockIdx.y;

    const f32x4 zero = {0.f, 0.f, 0.f, 0.f};
    f32x4 acc[4][4];
#pragma unroll
    for (int i = 0; i < 4; ++i)
#pragma unroll
        for (int j = 0; j < 4; ++j) acc[i][j] = zero;

    const int sr = tid >> 3;   // staging row 0..31 (stride 32)
    const int sc = tid & 7;    // staging 16B chunk 0..7
    const int q  = lane >> 4;  // quad
    const int rl = lane & 15;

    for (int kt = 0; kt < K; kt += 64) {
        uint4v va[4], vb[4];
#pragma unroll
        for (int i = 0; i < 4; ++i) {
            int row = sr + 32 * i;
            va[i] = *(const uint4v*)(A  + (size_t)(by * 128 + row) * K + kt + sc * 8);
            vb[i] = *(const uint4v*)(Bt + (size_t)(bx * 128 + row) * K + kt + sc * 8);
        }
        __syncthreads();
#pragma unroll
        for (int i = 0; i < 4; ++i) {
            int row = sr + 32 * i;
            *(uint4v*)(lsA + row * 64 + ((sc ^ (row & 7)) * 8)) = va[i];
            *(uint4v*)(lsB + row * 64 + ((sc ^ (row & 7)) * 8)) = vb[i];
        }
        __syncthreads();
#pragma unroll
        for (int s = 0; s < 2; ++s) {
            bf16x8 af[4], bfv[4];
#pragma unroll
            for (int i = 0; i < 4; ++i) {
                int Ra = wm * 64 + i * 16 + rl;
                af[i]  = *(const bf16x8*)(lsA + Ra * 64 + (((s * 4 + q) ^ (Ra & 7)) * 8));
                int Rb = wn * 64 + i * 16 + rl;
                bfv[i] = *(const bf16x8*)(lsB + Rb * 64 + (((s * 4 + q) ^ (Rb & 7)) * 8));
            }
#pragma unroll
            for (int i = 0; i < 4; ++i)
#pragma unroll
                for (int j = 0; j < 4; ++j)
                    acc[i][j] = __builtin_amdgcn_mfma_f32_16x16x32_bf16(af[i], bfv[j], acc[i][j], 0, 0, 0);
        }
    }
    // epilogue: C/D layout col=lane&15, row=quad*4+reg (m89-verified)
#pragma unroll
    for (int j = 0; j < 4; ++j) {
        int col = bx * 128 + wn * 64 + j * 16 + rl;
        float bv = bias ? bias[col] : 0.0f;
#pragma unroll
        for (int i = 0; i < 4; ++i) {
#pragma unroll
            for (int t = 0; t < 4; ++t) {
                int row = by * 128 + wm * 64 + i * 16 + q * 4 + t;
                C[(size_t)row * N + col] = f2bf(acc[i][j][t] + bv);
            }
        }
    }
}

// ---------------------------------------------------------------------------
// CSR build by dst (count -> scan -> scatter). Indices pre-clamped to [0,N).
// ---------------------------------------------------------------------------
__global__ void indeg_kernel(const int* __restrict__ eic, int* __restrict__ deg) {
    int e = blockIdx.x * 256 + threadIdx.x;
    if (e >= E_TOT) return;
    int dst = (e < E_EDGES) ? eic[E_EDGES + e] : (e - E_EDGES);
    atomicAdd(&deg[dst], 1);
}
__global__ __launch_bounds__(256) void scan_kernel(const int* __restrict__ deg, int* __restrict__ rowptr) {
    __shared__ int part[256];
    int t = threadIdx.x;
    int local[32];
    int s = 0;
#pragma unroll
    for (int i = 0; i < 32; ++i) { local[i] = deg[t * 32 + i]; s += local[i]; }
    part[t] = s;
    __syncthreads();
    for (int off = 1; off < 256; off <<= 1) {
        int v = (t >= off) ? part[t - off] : 0;
        __syncthreads();
        part[t] += v;
        __syncthreads();
    }
    int run = (t == 0) ? 0 : part[t - 1];
#pragma unroll
    for (int i = 0; i < 32; ++i) { rowptr[t * 32 + i] = run; run += local[i]; }
    if (t == 255) rowptr[N_NODES] = run;
}
__global__ void scatter_kernel(const int* __restrict__ eic, const int* __restrict__ rowptr,
                               int* __restrict__ fill, int* __restrict__ csr_src) {
    int e = blockIdx.x * 256 + threadIdx.x;
    if (e >= E_TOT) return;
    int src, dst;
    if (e < E_EDGES) { src = eic[e]; dst = eic[E_EDGES + e]; }
    else             { src = e - E_EDGES; dst = src; }
    int pos = rowptr[dst] + atomicAdd(&fill[dst], 1);
    csr_src[pos] = src;
}

// ---------------------------------------------------------------------------
// Attention logits: a_s[n,h] = <h[n,h,:], att_s[h,:]> (h bf16, att f32).
// One wave per (node, head).
// ---------------------------------------------------------------------------
__global__ __launch_bounds__(256) void att_kernel(
    const ushort_t* __restrict__ h, const float* __restrict__ att_s,
    const float* __restrict__ att_d, float* __restrict__ a_s, float* __restrict__ a_d,
    int heads, int stride)
{
    int gid  = blockIdx.x * 4 + (threadIdx.x >> 6);
    int lane = threadIdx.x & 63;
    int n = gid / heads, hd = gid % heads;
    const ushort_t* hp = h + (size_t)n * stride + hd * C_CH;
    const float* sp = att_s + hd * C_CH;
    const float* dp = att_d + hd * C_CH;
    float s1 = 0.f, s2 = 0.f;
    for (int i = lane; i < C_CH; i += 64) {
        float hv = bf2f(hp[i]);
        s1 += hv * sp[i];
        s2 += hv * dp[i];
    }
#pragma unroll
    for (int off = 32; off > 0; off >>= 1) {
        s1 += __shfl_down(s1, off);
        s2 += __shfl_down(s2, off);
    }
    if (lane == 0) { a_s[gid] = s1; a_d[gid] = s2; }
}

// ---------------------------------------------------------------------------
// Aggregation layer 1 (8 heads, 6144 ch): block per dst node, gather via CSR,
// per-head softmax over incoming edges, ELU(out + b1) -> bf16.
// Thread t owns 24 contiguous channels (all within one head since 24*32=768).
// ---------------------------------------------------------------------------
__global__ __launch_bounds__(256) void agg8_kernel(
    const ushort_t* __restrict__ h, const float* __restrict__ a_s, const float* __restrict__ a_d,
    const int* __restrict__ rowptr, const int* __restrict__ csr_src,
    const float* __restrict__ bias, ushort_t* __restrict__ out)
{
    const int n = blockIdx.x;
    const int tid = threadIdx.x;
    const int base = rowptr[n];
    const int deg  = rowptr[n + 1] - base;

    __shared__ float s_m[8], s_rd[8], s_adst[8];
    __shared__ int   s_src[64];
    __shared__ float s_w[64][8];

    if (tid < 8) {
        float adst = a_d[n * 8 + tid];
        float m = -1e30f;
        for (int e = 0; e < deg; ++e) {
            float scv = a_s[csr_src[base + e] * 8 + tid] + adst;
            scv = scv > 0.f ? scv : 0.2f * scv;
            m = fmaxf(m, scv);
        }
        float den = 0.f;
        for (int e = 0; e < deg; ++e) {
            float scv = a_s[csr_src[base + e] * 8 + tid] + adst;
            scv = scv > 0.f ? scv : 0.2f * scv;
            den += __expf(scv - m);
        }
        s_m[tid] = m; s_rd[tid] = 1.0f / (den + 1e-16f); s_adst[tid] = adst;
    }
    __syncthreads();

    float acc[24];
#pragma unroll
    for (int i = 0; i < 24; ++i) acc[i] = 0.f;
    const int c0 = tid * 24;
    const int myhd = tid >> 5;

    for (int cs = 0; cs < deg; cs += 64) {
        int cnt = min(64, deg - cs);
        __syncthreads();
        for (int idx = tid; idx < cnt; idx += 256) s_src[idx] = csr_src[base + cs + idx];
        __syncthreads();
        for (int idx = tid; idx < cnt * 8; idx += 256) {
            int e = idx >> 3, hd = idx & 7;
            float scv = a_s[s_src[e] * 8 + hd] + s_adst[hd];
            scv = scv > 0.f ? scv : 0.2f * scv;
            s_w[e][hd] = __expf(scv - s_m[hd]) * s_rd[hd];
        }
        __syncthreads();
        for (int e = 0; e < cnt; ++e) {
            const ushort_t* hp = h + (size_t)s_src[e] * F1 + c0;
            float w = s_w[e][myhd];
            ushort8 v0 = *(const ushort8*)(hp);
            ushort8 v1 = *(const ushort8*)(hp + 8);
            ushort8 v2 = *(const ushort8*)(hp + 16);
#pragma unroll
            for (int i = 0; i < 8; ++i) {
                acc[i]      += w * bf2f(v0[i]);
                acc[8 + i]  += w * bf2f(v1[i]);
                acc[16 + i] += w * bf2f(v2[i]);
            }
        }
    }
#pragma unroll
    for (int i = 0; i < 24; ++i) {
        float v = acc[i] + bias[c0 + i];
        v = v > 0.f ? v : (__expf(v) - 1.0f);   // ELU
        out[(size_t)n * F1 + c0 + i] = f2bf(v);
    }
}

// ---------------------------------------------------------------------------
// Aggregation layer 2 (1 head, 768 ch): same structure, + b2, no activation.
// ---------------------------------------------------------------------------
__global__ __launch_bounds__(256) void agg1_kernel(
    const ushort_t* __restrict__ h, const float* __restrict__ a_s, const float* __restrict__ a_d,
    const int* __restrict__ rowptr, const int* __restrict__ csr_src,
    const float* __restrict__ bias, ushort_t* __restrict__ out)
{
    const int n = blockIdx.x;
    const int tid = threadIdx.x;
    const int base = rowptr[n];
    const int deg  = rowptr[n + 1] - base;
    __shared__ float s_m, s_rd, s_adst;
    __shared__ int   s_src[64];
    __shared__ float s_w[64];
    if (tid == 0) {
        float adst = a_d[n];
        float m = -1e30f;
        for (int e = 0; e < deg; ++e) {
            float scv = a_s[csr_src[base + e]] + adst;
            scv = scv > 0.f ? scv : 0.2f * scv;
            m = fmaxf(m, scv);
        }
        float den = 0.f;
        for (int e = 0; e < deg; ++e) {
            float scv = a_s[csr_src[base + e]] + adst;
            scv = scv > 0.f ? scv : 0.2f * scv;
            den += __expf(scv - m);
        }
        s_m = m; s_rd = 1.0f / (den + 1e-16f); s_adst = adst;
    }
    __syncthreads();
    float acc0 = 0.f, acc1 = 0.f, acc2 = 0.f;
    const int c0 = tid * 3;
    for (int cs = 0; cs < deg; cs += 64) {
        int cnt = min(64, deg - cs);
        __syncthreads();
        for (int idx = tid; idx < cnt; idx += 256) s_src[idx] = csr_src[base + cs + idx];
        __syncthreads();
        for (int idx = tid; idx < cnt; idx += 256) {
            float scv = a_s[s_src[idx]] + s_adst;
            scv = scv > 0.f ? scv : 0.2f * scv;
            s_w[idx] = __expf(scv - s_m) * s_rd;
        }
        __syncthreads();
        for (int e = 0; e < cnt; ++e) {
            const ushort_t* hp = h + (size_t)s_src[e] * C_CH + c0;
            float w = s_w[e];
            acc0 += w * bf2f(hp[0]);
            acc1 += w * bf2f(hp[1]);
            acc2 += w * bf2f(hp[2]);
        }
    }
    out[(size_t)n * C_CH + c0 + 0] = f2bf(acc0 + bias[c0 + 0]);
    out[(size_t)n * C_CH + c0 + 1] = f2bf(acc1 + bias[c0 + 1]);
    out[(size_t)n * C_CH + c0 + 2] = f2bf(acc2 + bias[c0 + 2]);
}

// ---------------------------------------------------------------------------
// Build fc input rows: Afc[m] = concat(out2[mask[m]], xb[mask[m]])  (bf16)
// ---------------------------------------------------------------------------
__global__ void gatherfc_kernel(const ushort_t* __restrict__ out2, const ushort_t* __restrict__ xb,
                                const int* __restrict__ maskc, ushort_t* __restrict__ Afc)
{
    int m = blockIdx.x, t = threadIdx.x;
    int mi = maskc[m];
    const ushort_t* p1 = out2 + (size_t)mi * 768;
    const ushort_t* p2 = xb   + (size_t)mi * 768;
    for (int c = t; c < 768; c += 256) {
        Afc[(size_t)m * 1536 + c]       = p1[c];
        Afc[(size_t)m * 1536 + 768 + c] = p2[c];
    }
}

// ---------------------------------------------------------------------------
// Classifier: out[m, 0:2] = fc_out[m] @ cls_w + cls_b (f32 out). One wave/row.
// ---------------------------------------------------------------------------
__global__ __launch_bounds__(256) void cls_kernel(
    const ushort_t* __restrict__ fc_out, const float* __restrict__ cls_w,
    const float* __restrict__ cls_b, float* __restrict__ out)
{
    int m = blockIdx.x * 4 + (threadIdx.x >> 6);
    int lane = threadIdx.x & 63;
    float a0 = 0.f, a1 = 0.f;
    const ushort_t* row = fc_out + (size_t)m * 768;
    for (int i = lane; i < 768; i += 64) {
        float v = bf2f(row[i]);
        a0 += v * cls_w[i * 2 + 0];
        a1 += v * cls_w[i * 2 + 1];
    }
#pragma unroll
    for (int off = 32; off > 0; off >>= 1) {
        a0 += __shfl_down(a0, off);
        a1 += __shfl_down(a1, off);
    }
    if (lane == 0) {
        out[m * 2 + 0] = a0 + cls_b[0];
        out[m * 2 + 1] = a1 + cls_b[1];
    }
}

extern "C" void kernel_launch(void* const* d_in, const int* in_sizes, int n_in,
                              void* d_out, int out_size, void* d_ws, size_t ws_size,
                              hipStream_t stream)
{
    const float* x        = (const float*)d_in[0];
    const void*  ei_raw   = d_in[1];
    const void*  mask_raw = d_in[2];
    const float* W1       = (const float*)d_in[3];
    const float* att_src1 = (const float*)d_in[4];
    const float* att_dst1 = (const float*)d_in[5];
    const float* b1       = (const float*)d_in[6];
    const float* W2       = (const float*)d_in[7];
    const float* att_src2 = (const float*)d_in[8];
    const float* att_dst2 = (const float*)d_in[9];
    const float* b2       = (const float*)d_in[10];
    const float* fc_w     = (const float*)d_in[11];
    const float* fc_b     = (const float*)d_in[12];
    const float* cls_w    = (const float*)d_in[13];
    const float* cls_b    = (const float*)d_in[14];
    float* out = (float*)d_out;

    // ---- workspace layout ----
    char* ws = (char*)d_ws;
    size_t off = 0;
    auto alloc = [&](size_t bytes) { char* p = ws + off; off = (off + bytes + 255) & ~(size_t)255; return p; };
    int*   flags  = (int*)alloc(2 * 4);
    int*   eic    = (int*)alloc((size_t)2 * E_EDGES * 4);
    int*   maskc  = (int*)alloc((size_t)M_MASK * 4);
    int*   deg    = (int*)alloc(N_NODES * 4);
    int*   fill   = (int*)alloc(N_NODES * 4);
    int*   rowptr = (int*)alloc((N_NODES + 1) * 4);
    int*   csr    = (int*)alloc(E_TOT * 4);
    float* a_s1   = (float*)alloc((size_t)N_NODES * 8 * 4);
    float* a_d1   = (float*)alloc((size_t)N_NODES * 8 * 4);
    float* a_s2   = (float*)alloc((size_t)N_NODES * 4);
    float* a_d2   = (float*)alloc((size_t)N_NODES * 4);
    ushort_t* W1t  = (ushort_t*)alloc((size_t)D_IN * F1 * 2);
    ushort_t* W2t  = (ushort_t*)alloc((size_t)F1 * C_CH * 2);
    ushort_t* fcwt = (ushort_t*)alloc((size_t)1536 * 768 * 2);
    ushort_t* xb   = (ushort_t*)alloc((size_t)N_NODES * D_IN * 2);
    char* region1 = alloc((size_t)N_NODES * F1 * 2);   // h1, later h2/Afc/fcout
    char* region2 = alloc((size_t)N_NODES * F1 * 2);   // out1, later out2
    ushort_t* h1    = (ushort_t*)region1;
    ushort_t* h2    = (ushort_t*)region1;                   // after h1 dead (12.6MB)
    ushort_t* Afc   = (ushort_t*)(region1 + (16u << 20));   // 6.3MB @ 16MiB
    ushort_t* fcout = (ushort_t*)(region1 + (32u << 20));   // 3.1MB @ 32MiB
    ushort_t* out1  = (ushort_t*)region2;
    ushort_t* out2  = (ushort_t*)region2;                   // after out1 dead

    // ---- index conversion + CSR build ----
    init_kernel<<<N_NODES / 256, 256, 0, stream>>>(deg, fill, flags);
    detect_kernel<<<(E_EDGES + 255) / 256, 256, 0, stream>>>((const int*)ei_raw, E_EDGES, &flags[0]);
    detect_kernel<<<(M_MASK / 2 + 255) / 256, 256, 0, stream>>>((const int*)mask_raw, M_MASK / 2, &flags[1]);
    convert_idx_kernel<<<(2 * E_EDGES + 255) / 256, 256, 0, stream>>>(ei_raw, 2 * E_EDGES, &flags[0], eic);
    convert_idx_kernel<<<(M_MASK + 255) / 256, 256, 0, stream>>>(mask_raw, M_MASK, &flags[1], maskc);
    indeg_kernel<<<E_TOT / 256, 256, 0, stream>>>(eic, deg);
    scan_kernel<<<1, 256, 0, stream>>>(deg, rowptr);
    scatter_kernel<<<E_TOT / 256, 256, 0, stream>>>(eic, rowptr, fill, csr);

    // ---- f32 -> bf16 converts: x, and weight transposes to [N,K] ----
    cvt_bf16_kernel<<<(N_NODES * D_IN / 4 + 255) / 256, 256, 0, stream>>>(x, xb, N_NODES * D_IN / 4);
    transpose_cvt_kernel<<<dim3(F1 / 32, D_IN / 32), 256, 0, stream>>>(W1, W1t, D_IN, F1);
    transpose_cvt_kernel<<<dim3(C_CH / 32, F1 / 32), 256, 0, stream>>>(W2, W2t, F1, C_CH);
    transpose_cvt_kernel<<<dim3(768 / 32, 1536 / 32), 256, 0, stream>>>(fc_w, fcwt, 1536, 768);

    // ---- layer 1 ----
    gemm_bt_kernel<<<dim3(F1 / 128, N_NODES / 128), 256, 0, stream>>>(xb, W1t, h1, nullptr, N_NODES, F1, D_IN);
    att_kernel<<<(N_NODES * 8) / 4, 256, 0, stream>>>(h1, att_src1, att_dst1, a_s1, a_d1, 8, F1);
    agg8_kernel<<<N_NODES, 256, 0, stream>>>(h1, a_s1, a_d1, rowptr, csr, b1, out1);

    // ---- layer 2 ----  (h1 dead: region1 reused for h2)
    gemm_bt_kernel<<<dim3(C_CH / 128, N_NODES / 128), 256, 0, stream>>>(out1, W2t, h2, nullptr, N_NODES, C_CH, F1);
    att_kernel<<<N_NODES / 4, 256, 0, stream>>>(h2, att_src2, att_dst2, a_s2, a_d2, 1, C_CH);
    agg1_kernel<<<N_NODES, 256, 0, stream>>>(h2, a_s2, a_d2, rowptr, csr, b2, out2);  // out1 dead

    // ---- head ----
    gatherfc_kernel<<<M_MASK, 256, 0, stream>>>(out2, xb, maskc, Afc);
    gemm_bt_kernel<<<dim3(768 / 128, M_MASK / 128), 256, 0, stream>>>(Afc, fcwt, fcout, fc_b, M_MASK, 768, 1536);
    cls_kernel<<<M_MASK / 4, 256, 0, stream>>>(fcout, cls_w, cls_b, out);
}

// Round 4
// 546.051 us; speedup vs baseline: 1.0799x; 1.0799x over previous
//
#include <hip/hip_runtime.h>

typedef unsigned short ushort_t;
typedef __attribute__((ext_vector_type(8))) __bf16 bf16x8;
typedef __attribute__((ext_vector_type(8))) unsigned short ushort8;
typedef __attribute__((ext_vector_type(4))) unsigned short ushort4v;
typedef __attribute__((ext_vector_type(4))) float f32x4;

#define N_NODES 8192
#define NODE_MASK 8191
#define E_EDGES 32768
#define E_TOT   40960   /* E + N self loops */
#define M_MASK  2048
#define D_IN    768
#define C_CH    768
#define F1      6144    /* 8 heads * 768 */

typedef __attribute__((address_space(1))) const void* gas_ptr;
typedef __attribute__((address_space(3))) void* las_ptr;

__device__ __forceinline__ float bf2f(ushort_t u) {
    union { unsigned int i; float f; } v; v.i = ((unsigned int)u) << 16; return v.f;
}
__device__ __forceinline__ ushort_t f2bf(float f) {
    union { float f; unsigned int i; } v; v.f = f;
    unsigned int r = v.i + 0x7fffu + ((v.i >> 16) & 1u);
    return (ushort_t)(r >> 16);
}

// ---------------------------------------------------------------------------
// int64-vs-int32 detection + conversion of index arrays (clamped to [0,N)).
// ---------------------------------------------------------------------------
__global__ void init_kernel(int* deg, int* fill, int* flags) {
    int i = blockIdx.x * 256 + threadIdx.x;
    if (i < N_NODES) { deg[i] = 0; fill[i] = 0; }
    if (i < 2) flags[i] = 0;
}
__global__ void detect_kernel(const int* __restrict__ raw, int nhalf, int* __restrict__ flag) {
    int i = blockIdx.x * 256 + threadIdx.x;
    if (i < nhalf && raw[2 * i + 1] != 0) atomicOr(flag, 1);
}
__global__ void convert_idx_kernel(const void* __restrict__ raw, int n,
                                   const int* __restrict__ flag, int* __restrict__ out) {
    int i = blockIdx.x * 256 + threadIdx.x;
    if (i >= n) return;
    int v = (*flag) ? ((const int*)raw)[i] : (int)((const long long*)raw)[i];
    out[i] = v & NODE_MASK;
}

// ---------------------------------------------------------------------------
// f32 -> bf16 elementwise convert (vectorized)
// ---------------------------------------------------------------------------
__global__ void cvt_bf16_kernel(const float* __restrict__ in, ushort_t* __restrict__ out, int n4) {
    int i = blockIdx.x * 256 + threadIdx.x;
    if (i >= n4) return;
    f32x4 v = *(const f32x4*)(in + i * 4);
    ushort_t o0 = f2bf(v[0]), o1 = f2bf(v[1]), o2 = f2bf(v[2]), o3 = f2bf(v[3]);
    unsigned long long pk = (unsigned long long)o0 | ((unsigned long long)o1 << 16)
                          | ((unsigned long long)o2 << 32) | ((unsigned long long)o3 << 48);
    *(unsigned long long*)(out + i * 4) = pk;
}

// ---------------------------------------------------------------------------
// f32 -> bf16 transpose: out[c][r] = (bf16)in[r][c]; in is R x Ccols f32.
// ---------------------------------------------------------------------------
__global__ __launch_bounds__(256) void transpose_cvt_kernel(
    const float* __restrict__ in, ushort_t* __restrict__ out, int R, int Ccols)
{
    __shared__ ushort_t tile[32][33];
    int tx = threadIdx.x & 31, ty = threadIdx.x >> 5;
    int x  = blockIdx.x * 32 + tx;
    int y0 = blockIdx.y * 32;
#pragma unroll
    for (int i = 0; i < 4; ++i)
        tile[ty + i * 8][tx] = f2bf(in[(size_t)(y0 + ty + i * 8) * Ccols + x]);
    __syncthreads();
#pragma unroll
    for (int i = 0; i < 4; ++i)
        out[(size_t)(blockIdx.x * 32 + ty + i * 8) * R + y0 + tx] = tile[tx][ty + i * 8];
}

// ---------------------------------------------------------------------------
// bf16 MFMA GEMM:  C[M,N] = A[M,K] * Bt[N,K]^T  (+ optional f32 bias[N]) -> bf16
// 128x128 tile, BK=64, 256 threads. Staging via global_load_lds width=16
// (m97 structure). XOR swizzle applied on the GLOBAL source address so the
// wave-uniform-base+lane*16 LDS layout still yields <=2-way-bank ds_read_b128.
// ---------------------------------------------------------------------------
__global__ __launch_bounds__(256) void gemm_bt_kernel(
    const ushort_t* __restrict__ A, const ushort_t* __restrict__ Bt,
    ushort_t* __restrict__ C, const float* __restrict__ bias,
    int M, int N, int K)
{
    __shared__ ushort_t lsA[128 * 64];
    __shared__ ushort_t lsB[128 * 64];

    const int tid  = threadIdx.x;
    const int lane = tid & 63;
    const int wave = tid >> 6;
    const int wm = wave >> 1, wn = wave & 1;
    const int bx = blockIdx.x, by = blockIdx.y;

    const f32x4 zero = {0.f, 0.f, 0.f, 0.f};
    f32x4 acc[4][4];
#pragma unroll
    for (int i = 0; i < 4; ++i)
#pragma unroll
        for (int j = 0; j < 4; ++j) acc[i][j] = zero;

    const int l8 = lane >> 3;   // row within 8-row group
    const int c8 = lane & 7;    // 16B chunk slot
    const int q  = lane >> 4;   // quad
    const int rl = lane & 15;

    for (int kt = 0; kt < K; kt += 64) {
        __syncthreads();   // previous tile fully consumed
#pragma unroll
        for (int i = 0; i < 4; ++i) {
            int rbase = wave * 32 + i * 8;      // wave-uniform
            int row   = rbase + l8;             // per-lane
            int gch   = c8 ^ (row & 7);         // swizzle on source
            const ushort_t* gA = A  + (size_t)(by * 128 + row) * K + kt + gch * 8;
            const ushort_t* gB = Bt + (size_t)(bx * 128 + row) * K + kt + gch * 8;
            __builtin_amdgcn_global_load_lds((gas_ptr)gA, (las_ptr)(lsA + rbase * 64), 16, 0, 0);
            __builtin_amdgcn_global_load_lds((gas_ptr)gB, (las_ptr)(lsB + rbase * 64), 16, 0, 0);
        }
        __syncthreads();   // vmcnt drained by barrier semantics
#pragma unroll
        for (int s = 0; s < 2; ++s) {
            bf16x8 af[4], bfv[4];
#pragma unroll
            for (int i = 0; i < 4; ++i) {
                int Ra = wm * 64 + i * 16 + rl;
                af[i]  = *(const bf16x8*)(lsA + Ra * 64 + (((s * 4 + q) ^ (Ra & 7)) * 8));
                int Rb = wn * 64 + i * 16 + rl;
                bfv[i] = *(const bf16x8*)(lsB + Rb * 64 + (((s * 4 + q) ^ (Rb & 7)) * 8));
            }
#pragma unroll
            for (int i = 0; i < 4; ++i)
#pragma unroll
                for (int j = 0; j < 4; ++j)
                    acc[i][j] = __builtin_amdgcn_mfma_f32_16x16x32_bf16(af[i], bfv[j], acc[i][j], 0, 0, 0);
        }
    }
    // epilogue: C/D layout col=lane&15, row=quad*4+reg (m89-verified)
#pragma unroll
    for (int j = 0; j < 4; ++j) {
        int col = bx * 128 + wn * 64 + j * 16 + rl;
        float bv = bias ? bias[col] : 0.0f;
#pragma unroll
        for (int i = 0; i < 4; ++i) {
#pragma unroll
            for (int t = 0; t < 4; ++t) {
                int row = by * 128 + wm * 64 + i * 16 + q * 4 + t;
                C[(size_t)row * N + col] = f2bf(acc[i][j][t] + bv);
            }
        }
    }
}

// ---------------------------------------------------------------------------
// CSR build by dst (count -> scan -> scatter). Indices pre-clamped to [0,N).
// ---------------------------------------------------------------------------
__global__ void indeg_kernel(const int* __restrict__ eic, int* __restrict__ deg) {
    int e = blockIdx.x * 256 + threadIdx.x;
    if (e >= E_TOT) return;
    int dst = (e < E_EDGES) ? eic[E_EDGES + e] : (e - E_EDGES);
    atomicAdd(&deg[dst], 1);
}
__global__ __launch_bounds__(256) void scan_kernel(const int* __restrict__ deg, int* __restrict__ rowptr) {
    __shared__ int part[256];
    int t = threadIdx.x;
    int local[32];
    int s = 0;
#pragma unroll
    for (int i = 0; i < 32; ++i) { local[i] = deg[t * 32 + i]; s += local[i]; }
    part[t] = s;
    __syncthreads();
    for (int off = 1; off < 256; off <<= 1) {
        int v = (t >= off) ? part[t - off] : 0;
        __syncthreads();
        part[t] += v;
        __syncthreads();
    }
    int run = (t == 0) ? 0 : part[t - 1];
#pragma unroll
    for (int i = 0; i < 32; ++i) { rowptr[t * 32 + i] = run; run += local[i]; }
    if (t == 255) rowptr[N_NODES] = run;
}
__global__ void scatter_kernel(const int* __restrict__ eic, const int* __restrict__ rowptr,
                               int* __restrict__ fill, int* __restrict__ csr_src) {
    int e = blockIdx.x * 256 + threadIdx.x;
    if (e >= E_TOT) return;
    int src, dst;
    if (e < E_EDGES) { src = eic[e]; dst = eic[E_EDGES + e]; }
    else             { src = e - E_EDGES; dst = src; }
    int pos = rowptr[dst] + atomicAdd(&fill[dst], 1);
    csr_src[pos] = src;
}

// ---------------------------------------------------------------------------
// Attention logits: a_s[n,h] = <h[n,h,:], att_s[h,:]> (h bf16, att f32).
// One wave per (node, head); lane owns 3 x ushort4 (12 ch).
// ---------------------------------------------------------------------------
__global__ __launch_bounds__(256) void att_kernel(
    const ushort_t* __restrict__ h, const float* __restrict__ att_s,
    const float* __restrict__ att_d, float* __restrict__ a_s, float* __restrict__ a_d,
    int heads, int stride)
{
    int gid  = blockIdx.x * 4 + (threadIdx.x >> 6);
    int lane = threadIdx.x & 63;
    int n = gid / heads, hd = gid % heads;
    const ushort_t* hp = h + (size_t)n * stride + hd * C_CH;
    const float* sp = att_s + hd * C_CH;
    const float* dp = att_d + hd * C_CH;
    float s1 = 0.f, s2 = 0.f;
#pragma unroll
    for (int j = 0; j < 3; ++j) {
        int o = j * 256 + lane * 4;
        ushort4v hv = *(const ushort4v*)(hp + o);
        f32x4 sv = *(const f32x4*)(sp + o);
        f32x4 dv = *(const f32x4*)(dp + o);
#pragma unroll
        for (int k = 0; k < 4; ++k) {
            float f = bf2f(hv[k]);
            s1 += f * sv[k];
            s2 += f * dv[k];
        }
    }
#pragma unroll
    for (int off = 32; off > 0; off >>= 1) {
        s1 += __shfl_down(s1, off);
        s2 += __shfl_down(s2, off);
    }
    if (lane == 0) { a_s[gid] = s1; a_d[gid] = s2; }
}

// ---------------------------------------------------------------------------
// Aggregation layer 1 (8 heads, 6144 ch): grid (node, half). Each block does
// 3072 channels with 192 threads x 16 ch; per-head softmax over incoming
// edges; edge loop unrolled x2 (4 b128 loads in flight); ELU(out+b1) -> bf16.
// ---------------------------------------------------------------------------
__global__ __launch_bounds__(192) void agg8_kernel(
    const ushort_t* __restrict__ h, const float* __restrict__ a_s, const float* __restrict__ a_d,
    const int* __restrict__ rowptr, const int* __restrict__ csr_src,
    const float* __restrict__ bias, ushort_t* __restrict__ out)
{
    const int n = blockIdx.x;
    const int half = blockIdx.y;
    const int tid = threadIdx.x;
    const int base = rowptr[n];
    const int deg  = rowptr[n + 1] - base;

    __shared__ float s_m[8], s_rd[8], s_adst[8];
    __shared__ int   s_src[64];
    __shared__ float s_w[64][8];

    if (tid < 8) {
        float adst = a_d[n * 8 + tid];
        float m = -1e30f;
        for (int e = 0; e < deg; ++e) {
            float scv = a_s[csr_src[base + e] * 8 + tid] + adst;
            scv = scv > 0.f ? scv : 0.2f * scv;
            m = fmaxf(m, scv);
        }
        float den = 0.f;
        for (int e = 0; e < deg; ++e) {
            float scv = a_s[csr_src[base + e] * 8 + tid] + adst;
            scv = scv > 0.f ? scv : 0.2f * scv;
            den += __expf(scv - m);
        }
        s_m[tid] = m; s_rd[tid] = 1.0f / (den + 1e-16f); s_adst[tid] = adst;
    }
    __syncthreads();

    float acc[16];
#pragma unroll
    for (int i = 0; i < 16; ++i) acc[i] = 0.f;
    const int c0   = half * 3072 + tid * 16;
    const int myhd = (half << 2) + tid / 48;

    for (int cs = 0; cs < deg; cs += 64) {
        int cnt = min(64, deg - cs);
        __syncthreads();
        for (int idx = tid; idx < cnt; idx += 192) s_src[idx] = csr_src[base + cs + idx];
        __syncthreads();
        for (int idx = tid; idx < cnt * 8; idx += 192) {
            int e = idx >> 3, hd = idx & 7;
            float scv = a_s[s_src[e] * 8 + hd] + s_adst[hd];
            scv = scv > 0.f ? scv : 0.2f * scv;
            s_w[e][hd] = __expf(scv - s_m[hd]) * s_rd[hd];
        }
        __syncthreads();
        int e = 0;
        for (; e + 1 < cnt; e += 2) {
            const ushort_t* hp0 = h + (size_t)s_src[e] * F1 + c0;
            const ushort_t* hp1 = h + (size_t)s_src[e + 1] * F1 + c0;
            ushort8 a0 = *(const ushort8*)(hp0);
            ushort8 a1 = *(const ushort8*)(hp0 + 8);
            ushort8 b0 = *(const ushort8*)(hp1);
            ushort8 b1 = *(const ushort8*)(hp1 + 8);
            float w0 = s_w[e][myhd], w1 = s_w[e + 1][myhd];
#pragma unroll
            for (int i = 0; i < 8; ++i) {
                acc[i]     += w0 * bf2f(a0[i]) + w1 * bf2f(b0[i]);
                acc[8 + i] += w0 * bf2f(a1[i]) + w1 * bf2f(b1[i]);
            }
        }
        if (e < cnt) {
            const ushort_t* hp0 = h + (size_t)s_src[e] * F1 + c0;
            ushort8 a0 = *(const ushort8*)(hp0);
            ushort8 a1 = *(const ushort8*)(hp0 + 8);
            float w0 = s_w[e][myhd];
#pragma unroll
            for (int i = 0; i < 8; ++i) {
                acc[i]     += w0 * bf2f(a0[i]);
                acc[8 + i] += w0 * bf2f(a1[i]);
            }
        }
    }
#pragma unroll
    for (int i = 0; i < 16; ++i) {
        float v = acc[i] + bias[c0 + i];
        v = v > 0.f ? v : (__expf(v) - 1.0f);   // ELU
        out[(size_t)n * F1 + c0 + i] = f2bf(v);
    }
}

// ---------------------------------------------------------------------------
// Aggregation layer 2 (1 head, 768 ch): block per node, + b2, no activation.
// ---------------------------------------------------------------------------
__global__ __launch_bounds__(256) void agg1_kernel(
    const ushort_t* __restrict__ h, const float* __restrict__ a_s, const float* __restrict__ a_d,
    const int* __restrict__ rowptr, const int* __restrict__ csr_src,
    const float* __restrict__ bias, ushort_t* __restrict__ out)
{
    const int n = blockIdx.x;
    const int tid = threadIdx.x;
    const int base = rowptr[n];
    const int deg  = rowptr[n + 1] - base;
    __shared__ float s_m, s_rd, s_adst;
    __shared__ int   s_src[64];
    __shared__ float s_w[64];
    if (tid == 0) {
        float adst = a_d[n];
        float m = -1e30f;
        for (int e = 0; e < deg; ++e) {
            float scv = a_s[csr_src[base + e]] + adst;
            scv = scv > 0.f ? scv : 0.2f * scv;
            m = fmaxf(m, scv);
        }
        float den = 0.f;
        for (int e = 0; e < deg; ++e) {
            float scv = a_s[csr_src[base + e]] + adst;
            scv = scv > 0.f ? scv : 0.2f * scv;
            den += __expf(scv - m);
        }
        s_m = m; s_rd = 1.0f / (den + 1e-16f); s_adst = adst;
    }
    __syncthreads();
    float acc0 = 0.f, acc1 = 0.f, acc2 = 0.f;
    const int c0 = tid * 3;
    for (int cs = 0; cs < deg; cs += 64) {
        int cnt = min(64, deg - cs);
        __syncthreads();
        for (int idx = tid; idx < cnt; idx += 256) s_src[idx] = csr_src[base + cs + idx];
        __syncthreads();
        for (int idx = tid; idx < cnt; idx += 256) {
            float scv = a_s[s_src[idx]] + s_adst;
            scv = scv > 0.f ? scv : 0.2f * scv;
            s_w[idx] = __expf(scv - s_m) * s_rd;
        }
        __syncthreads();
        for (int e = 0; e < cnt; ++e) {
            const ushort_t* hp = h + (size_t)s_src[e] * C_CH + c0;
            float w = s_w[e];
            acc0 += w * bf2f(hp[0]);
            acc1 += w * bf2f(hp[1]);
            acc2 += w * bf2f(hp[2]);
        }
    }
    out[(size_t)n * C_CH + c0 + 0] = f2bf(acc0 + bias[c0 + 0]);
    out[(size_t)n * C_CH + c0 + 1] = f2bf(acc1 + bias[c0 + 1]);
    out[(size_t)n * C_CH + c0 + 2] = f2bf(acc2 + bias[c0 + 2]);
}

// ---------------------------------------------------------------------------
// Build fc input rows: Afc[m] = concat(out2[mask[m]], xb[mask[m]])  (bf16)
// ---------------------------------------------------------------------------
__global__ void gatherfc_kernel(const ushort_t* __restrict__ out2, const ushort_t* __restrict__ xb,
                                const int* __restrict__ maskc, ushort_t* __restrict__ Afc)
{
    int m = blockIdx.x, t = threadIdx.x;
    int mi = maskc[m];
    const ushort_t* p1 = out2 + (size_t)mi * 768;
    const ushort_t* p2 = xb   + (size_t)mi * 768;
    for (int c = t; c < 768; c += 256) {
        Afc[(size_t)m * 1536 + c]       = p1[c];
        Afc[(size_t)m * 1536 + 768 + c] = p2[c];
    }
}

// ---------------------------------------------------------------------------
// Classifier: out[m, 0:2] = fc_out[m] @ cls_w + cls_b (f32 out). One wave/row.
// ---------------------------------------------------------------------------
__global__ __launch_bounds__(256) void cls_kernel(
    const ushort_t* __restrict__ fc_out, const float* __restrict__ cls_w,
    const float* __restrict__ cls_b, float* __restrict__ out)
{
    int m = blockIdx.x * 4 + (threadIdx.x >> 6);
    int lane = threadIdx.x & 63;
    float a0 = 0.f, a1 = 0.f;
    const ushort_t* row = fc_out + (size_t)m * 768;
    for (int i = lane; i < 768; i += 64) {
        float v = bf2f(row[i]);
        a0 += v * cls_w[i * 2 + 0];
        a1 += v * cls_w[i * 2 + 1];
    }
#pragma unroll
    for (int off = 32; off > 0; off >>= 1) {
        a0 += __shfl_down(a0, off);
        a1 += __shfl_down(a1, off);
    }
    if (lane == 0) {
        out[m * 2 + 0] = a0 + cls_b[0];
        out[m * 2 + 1] = a1 + cls_b[1];
    }
}

extern "C" void kernel_launch(void* const* d_in, const int* in_sizes, int n_in,
                              void* d_out, int out_size, void* d_ws, size_t ws_size,
                              hipStream_t stream)
{
    const float* x        = (const float*)d_in[0];
    const void*  ei_raw   = d_in[1];
    const void*  mask_raw = d_in[2];
    const float* W1       = (const float*)d_in[3];
    const float* att_src1 = (const float*)d_in[4];
    const float* att_dst1 = (const float*)d_in[5];
    const float* b1       = (const float*)d_in[6];
    const float* W2       = (const float*)d_in[7];
    const float* att_src2 = (const float*)d_in[8];
    const float* att_dst2 = (const float*)d_in[9];
    const float* b2       = (const float*)d_in[10];
    const float* fc_w     = (const float*)d_in[11];
    const float* fc_b     = (const float*)d_in[12];
    const float* cls_w    = (const float*)d_in[13];
    const float* cls_b    = (const float*)d_in[14];
    float* out = (float*)d_out;

    // ---- workspace layout ----
    char* ws = (char*)d_ws;
    size_t off = 0;
    auto alloc = [&](size_t bytes) { char* p = ws + off; off = (off + bytes + 255) & ~(size_t)255; return p; };
    int*   flags  = (int*)alloc(2 * 4);
    int*   eic    = (int*)alloc((size_t)2 * E_EDGES * 4);
    int*   maskc  = (int*)alloc((size_t)M_MASK * 4);
    int*   deg    = (int*)alloc(N_NODES * 4);
    int*   fill   = (int*)alloc(N_NODES * 4);
    int*   rowptr = (int*)alloc((N_NODES + 1) * 4);
    int*   csr    = (int*)alloc(E_TOT * 4);
    float* a_s1   = (float*)alloc((size_t)N_NODES * 8 * 4);
    float* a_d1   = (float*)alloc((size_t)N_NODES * 8 * 4);
    float* a_s2   = (float*)alloc((size_t)N_NODES * 4);
    float* a_d2   = (float*)alloc((size_t)N_NODES * 4);
    ushort_t* W1t  = (ushort_t*)alloc((size_t)D_IN * F1 * 2);
    ushort_t* W2t  = (ushort_t*)alloc((size_t)F1 * C_CH * 2);
    ushort_t* fcwt = (ushort_t*)alloc((size_t)1536 * 768 * 2);
    ushort_t* xb   = (ushort_t*)alloc((size_t)N_NODES * D_IN * 2);
    char* region1 = alloc((size_t)N_NODES * F1 * 2);   // h1, later h2/Afc/fcout
    char* region2 = alloc((size_t)N_NODES * F1 * 2);   // out1, later out2
    ushort_t* h1    = (ushort_t*)region1;
    ushort_t* h2    = (ushort_t*)region1;                   // after h1 dead (12.6MB)
    ushort_t* Afc   = (ushort_t*)(region1 + (16u << 20));   // 6.3MB @ 16MiB
    ushort_t* fcout = (ushort_t*)(region1 + (32u << 20));   // 3.1MB @ 32MiB
    ushort_t* out1  = (ushort_t*)region2;
    ushort_t* out2  = (ushort_t*)region2;                   // after out1 dead

    // ---- index conversion + CSR build ----
    init_kernel<<<N_NODES / 256, 256, 0, stream>>>(deg, fill, flags);
    detect_kernel<<<(E_EDGES + 255) / 256, 256, 0, stream>>>((const int*)ei_raw, E_EDGES, &flags[0]);
    detect_kernel<<<(M_MASK / 2 + 255) / 256, 256, 0, stream>>>((const int*)mask_raw, M_MASK / 2, &flags[1]);
    convert_idx_kernel<<<(2 * E_EDGES + 255) / 256, 256, 0, stream>>>(ei_raw, 2 * E_EDGES, &flags[0], eic);
    convert_idx_kernel<<<(M_MASK + 255) / 256, 256, 0, stream>>>(mask_raw, M_MASK, &flags[1], maskc);
    indeg_kernel<<<E_TOT / 256, 256, 0, stream>>>(eic, deg);
    scan_kernel<<<1, 256, 0, stream>>>(deg, rowptr);
    scatter_kernel<<<E_TOT / 256, 256, 0, stream>>>(eic, rowptr, fill, csr);

    // ---- f32 -> bf16 converts: x, and weight transposes to [N,K] ----
    cvt_bf16_kernel<<<(N_NODES * D_IN / 4 + 255) / 256, 256, 0, stream>>>(x, xb, N_NODES * D_IN / 4);
    transpose_cvt_kernel<<<dim3(F1 / 32, D_IN / 32), 256, 0, stream>>>(W1, W1t, D_IN, F1);
    transpose_cvt_kernel<<<dim3(C_CH / 32, F1 / 32), 256, 0, stream>>>(W2, W2t, F1, C_CH);
    transpose_cvt_kernel<<<dim3(768 / 32, 1536 / 32), 256, 0, stream>>>(fc_w, fcwt, 1536, 768);

    // ---- layer 1 ----
    gemm_bt_kernel<<<dim3(F1 / 128, N_NODES / 128), 256, 0, stream>>>(xb, W1t, h1, nullptr, N_NODES, F1, D_IN);
    att_kernel<<<(N_NODES * 8) / 4, 256, 0, stream>>>(h1, att_src1, att_dst1, a_s1, a_d1, 8, F1);
    agg8_kernel<<<dim3(N_NODES, 2), 192, 0, stream>>>(h1, a_s1, a_d1, rowptr, csr, b1, out1);

    // ---- layer 2 ----  (h1 dead: region1 reused for h2)
    gemm_bt_kernel<<<dim3(C_CH / 128, N_NODES / 128), 256, 0, stream>>>(out1, W2t, h2, nullptr, N_NODES, C_CH, F1);
    att_kernel<<<N_NODES / 4, 256, 0, stream>>>(h2, att_src2, att_dst2, a_s2, a_d2, 1, C_CH);
    agg1_kernel<<<N_NODES, 256, 0, stream>>>(h2, a_s2, a_d2, rowptr, csr, b2, out2);  // out1 dead

    // ---- head ----
    gatherfc_kernel<<<M_MASK, 256, 0, stream>>>(out2, xb, maskc, Afc);
    gemm_bt_kernel<<<dim3(768 / 128, M_MASK / 128), 256, 0, stream>>>(Afc, fcwt, fcout, fc_b, M_MASK, 768, 1536);
    cls_kernel<<<M_MASK / 4, 256, 0, stream>>>(fcout, cls_w, cls_b, out);
}